// Round 8
// baseline (220.675 us; speedup 1.0000x reference)
//
#include <hip/hip_runtime.h>

// Problem constants (B=4, S=4096, D=2048, E=8, K=2, cap_factor=1.25)
#define TOKENS      16384
#define DIM         2048
#define D4          512          // DIM / 4 (float4 units)
#define NE          8            // experts
#define CAPACITY    5120         // int(16384*2/8*1.25)
#define NASSIGN     (TOKENS * 2) // 32768 top-k assignments

#define NTHREADS      512        // 8 waves/block
#define TOK_PER_BLOCK 16
#define NBLOCKS       (TOKENS / TOK_PER_BLOCK)   // 1024

// d_out layout (all float32, tuple order):
//   [0, 32768)        expert_indices as float  [B,S,K]
//   [32768, 65536)    expert_weights           [B,S,K]
//   [65536]           load_balance_loss
//   [65537, 98305)    expert_mask              [B,S,K]

__device__ __forceinline__ float dot4(const float4 a, const float4 b) {
    return a.x * b.x + a.y * b.y + a.z * b.z + a.w * b.w;
}

// Copy-kernel-shaped router (r4/r7 post-mortem: ANY per-token w-sweep —
// LDS or L1 — plus an LDS-capped 16 waves/CU pins effective BW at ~2.2 TB/s).
// Here w lives in REGISTERS, dim-sliced: wave g owns dims [g*256,(g+1)*256);
// lane = (expert e=lane&7, sub s=lane>>3); wf[8] (32 VGPRs) covers all 8
// experts. Per token per wave: 8 dwordx4 loads (one 128B line each, 8-lane
// address duplication coalesces) + 32 FMA + 3 shuffles. No LDS tile -> 32
// waves/CU; live set ~110 VGPR -> no spill even at the 128 default budget.
__global__ __launch_bounds__(NTHREADS) void router_main(
    const float* __restrict__ x, const float* __restrict__ wg,
    float* __restrict__ out_idx, float* __restrict__ out_w,
    float* __restrict__ imp_g, int* __restrict__ cnt_g)
{
    __shared__ float part[TOK_PER_BLOCK][8][9];  // [token][wave g][expert], padded
    __shared__ float logits[TOK_PER_BLOCK][9];
    __shared__ float imp_lds[NE];
    __shared__ int   cnt_lds[NE];

    const int tid  = threadIdx.x;
    const int lane = tid & 63;
    const int g    = tid >> 6;        // wave id = dim-group (256 dims)
    const int e    = lane & 7;        // expert owned by this lane
    const int s    = lane >> 3;       // sub-chunk 0..7

    if (tid < NE) { imp_lds[tid] = 0.f; cnt_lds[tid] = 0; }

    // w fragment: wf[k] = w[e][g*256 + (s+8k)*4 .. +4), k=0..7   (32 VGPRs)
    const float4* w4    = (const float4*)wg;
    const float4* wbase = w4 + e * D4 + g * 64 + s;
    float4 wf[8];
#pragma unroll
    for (int k = 0; k < 8; k++) wf[k] = wbase[8 * k];

    const int tok0 = blockIdx.x * TOK_PER_BLOCK;
    const float4* xbase = (const float4*)x + (size_t)tok0 * D4 + g * 64 + s;

    // 2-token software pipeline over the block's 16 tokens.
    float4 xa[8], xb[8];
#pragma unroll
    for (int k = 0; k < 8; k++) xa[k] = xbase[8 * k];

#pragma unroll 1
    for (int t = 0; t < TOK_PER_BLOCK; t += 2) {
        const float4* xp1 = xbase + (size_t)(t + 1) * D4;
#pragma unroll
        for (int k = 0; k < 8; k++) xb[k] = xp1[8 * k];

        float acc = dot4(xa[0], wf[0]);
#pragma unroll
        for (int k = 1; k < 8; k++) acc += dot4(xa[k], wf[k]);
        acc += __shfl_xor(acc, 8, 64);    // reduce over s (lane bits 3..5)
        acc += __shfl_xor(acc, 16, 64);
        acc += __shfl_xor(acc, 32, 64);
        if (lane < 8) part[t][g][lane] = acc;

        if (t + 2 < TOK_PER_BLOCK) {
            const float4* xp2 = xbase + (size_t)(t + 2) * D4;
#pragma unroll
            for (int k = 0; k < 8; k++) xa[k] = xp2[8 * k];
        }

        float accb = dot4(xb[0], wf[0]);
#pragma unroll
        for (int k = 1; k < 8; k++) accb += dot4(xb[k], wf[k]);
        accb += __shfl_xor(accb, 8, 64);
        accb += __shfl_xor(accb, 16, 64);
        accb += __shfl_xor(accb, 32, 64);
        if (lane < 8) part[t + 1][g][lane] = accb;
    }

    __syncthreads();

    // cross-wave reduce: thread (t,e) sums the 8 wave partials (2-way banks, free)
    if (tid < TOK_PER_BLOCK * NE) {
        const int tt = tid >> 3, ee = tid & 7;
        float sum = 0.f;
#pragma unroll
        for (int gg = 0; gg < 8; gg++) sum += part[tt][gg][ee];
        logits[tt][ee] = sum;
    }
    __syncthreads();

    // scalar phase: one thread per token (16 parallel tokens, no serial lane<2)
    if (tid < TOK_PER_BLOCK) {
        const int t = tok0 + tid;
        float v[NE];
#pragma unroll
        for (int k = 0; k < NE; k++) v[k] = logits[tid][k];

        // softmax over 8 (importance accumulation)
        float m = v[0];
#pragma unroll
        for (int k = 1; k < NE; k++) m = fmaxf(m, v[k]);
        float pe[NE], ssum = 0.f;
#pragma unroll
        for (int k = 0; k < NE; k++) { pe[k] = expf(v[k] - m); ssum += pe[k]; }
        const float inv = 1.f / ssum;
#pragma unroll
        for (int k = 0; k < NE; k++) atomicAdd(&imp_lds[k], pe[k] * inv);

        // top-2 (ties -> lowest index, jax top_k semantics)
        int i1 = 0; float v1 = v[0];
#pragma unroll
        for (int k = 1; k < NE; k++) { if (v[k] > v1) { v1 = v[k]; i1 = k; } }
        int i2 = -1; float v2 = -3.4e38f;
#pragma unroll
        for (int k = 0; k < NE; k++) { if (k != i1 && v[k] > v2) { v2 = v[k]; i2 = k; } }

        const float w1 = 1.f / (1.f + expf(v2 - v1));   // renormalized pair
        atomicAdd(&cnt_lds[i1], 1);
        atomicAdd(&cnt_lds[i2], 1);

        out_idx[2 * t]     = (float)i1;
        out_idx[2 * t + 1] = (float)i2;
        out_w[2 * t]       = w1;
        out_w[2 * t + 1]   = 1.f - w1;
    }

    __syncthreads();
    if (tid < NE)          atomicAdd(&imp_g[tid], imp_lds[tid]);
    else if (tid < 2 * NE) atomicAdd(&cnt_g[tid - NE], cnt_lds[tid - NE]);
}

// Capacity mask (exact rank rule, matches lexsort((-wf, idxf)) + rank<capacity)
// plus the load-balance loss scalar.
__global__ void mask_loss_kernel(
    const float* __restrict__ out_idx, const float* __restrict__ out_w,
    float* __restrict__ mask, float* __restrict__ loss_out,
    const float* __restrict__ imp_g, const int* __restrict__ cnt_g)
{
    const int i = blockIdx.x * blockDim.x + threadIdx.x;
    if (i < NASSIGN) {
        const int e = (int)out_idx[i];
        const int c = cnt_g[e];
        float mk = 1.f;
        if (c > CAPACITY) {   // statistically never taken; exact fallback
            const float wi = out_w[i];
            int rank = 0;
            for (int j = 0; j < NASSIGN; j++) {
                if ((int)out_idx[j] == e) {
                    const float wj = out_w[j];
                    if (wj > wi || (wj == wi && j < i)) rank++;
                }
            }
            mk = (rank < CAPACITY) ? 1.f : 0.f;
        }
        mask[i] = mk;
    }
    if (blockIdx.x == 0 && threadIdx.x == 0) {
        float si = 0.f, sc = 0.f, dot = 0.f;
#pragma unroll
        for (int e = 0; e < NE; e++) {
            const float im = imp_g[e];
            const float ct = (float)cnt_g[e];
            si += im; sc += ct; dot += im * ct;
        }
        loss_out[0] = (float)NE * dot / (si * sc);
    }
}

extern "C" void kernel_launch(void* const* d_in, const int* in_sizes, int n_in,
                              void* d_out, int out_size, void* d_ws, size_t ws_size,
                              hipStream_t stream)
{
    const float* x  = (const float*)d_in[0];   // [4,4096,2048] f32
    const float* wg = (const float*)d_in[1];   // [8,2048] f32

    float* out      = (float*)d_out;
    float* out_idx  = out;            // 32768
    float* out_w    = out + 32768;    // 32768
    float* loss     = out + 65536;    // 1
    float* mask     = out + 65537;    // 32768

    float* imp_g = (float*)d_ws;                     // 8 f32
    int*   cnt_g = (int*)((char*)d_ws + 64);         // 8 i32

    hipMemsetAsync(d_ws, 0, 128, stream);

    router_main<<<NBLOCKS, NTHREADS, 0, stream>>>(x, wg, out_idx, out_w, imp_g, cnt_g);
    mask_loss_kernel<<<(NASSIGN + NTHREADS - 1) / NTHREADS, NTHREADS, 0, stream>>>(
        out_idx, out_w, mask, loss, imp_g, cnt_g);
}

// Round 9
// 220.021 us; speedup vs baseline: 1.0030x; 1.0030x over previous
//
#include <hip/hip_runtime.h>

// Problem constants (B=4, S=4096, D=2048, E=8, K=2, cap_factor=1.25)
#define TOKENS      16384
#define DIM         2048
#define D4          512          // DIM / 4 (float4 units)
#define NE          8            // experts
#define CAPACITY    5120         // int(16384*2/8*1.25)
#define NASSIGN     (TOKENS * 2) // 32768 top-k assignments

#define NTHREADS      512        // 8 waves/block
#define TOK_PER_BLOCK 32         // 512 blocks x 32 tokens = 16384
#define NBLOCKS       (TOKENS / TOK_PER_BLOCK)   // 512

typedef float fvec4 __attribute__((ext_vector_type(4)));
typedef float fvec2 __attribute__((ext_vector_type(2)));

// d_out layout (all float32, tuple order):
//   [0, 32768)        expert_indices as float  [B,S,K]
//   [32768, 65536)    expert_weights           [B,S,K]
//   [65536]           load_balance_loss
//   [65537, 98305)    expert_mask              [B,S,K]

__device__ __forceinline__ float dot4(const fvec4 a, const fvec4 b) {
    return a.x * b.x + a.y * b.y + a.z * b.z + a.w * b.w;
}

// x is read-once streaming data: non-temporal load (skip cache allocation).
__device__ __forceinline__ fvec4 ntload(const fvec4* p) {
    return __builtin_nontemporal_load(p);
}

// Reg-w router, v2 (r8 post-mortem): every structure plateaus at ~2.6 TB/s
// read while fills do 7 TB/s -> read ceiling is ~3 TB/s; get closer to it by
// (1) halving w traffic (32 tokens/block: w-reads 67->33 MB), (2) FORCING
// 2-token load depth with named A/B buffers + sched_barrier(0) (r8's VGPR=56
// proved the compiler sank the loads -> depth ~0), (3) nontemporal x loads.
// Live set ~114 VGPR < 128 default budget; NO launch_bounds min-arg (r6).
__global__ __launch_bounds__(NTHREADS) void router_main(
    const float* __restrict__ x, const float* __restrict__ wg,
    float* __restrict__ out_idx, float* __restrict__ out_w,
    float* __restrict__ imp_g, int* __restrict__ cnt_g)
{
    __shared__ float part[TOK_PER_BLOCK][8][9];  // [token][wave g][expert], padded
    __shared__ float logits[TOK_PER_BLOCK][9];
    __shared__ float imp_lds[NE];
    __shared__ int   cnt_lds[NE];

    const int tid  = threadIdx.x;
    const int lane = tid & 63;
    const int g    = tid >> 6;        // wave id = dim-group (256 dims)
    const int e    = lane & 7;        // expert owned by this lane
    const int s    = lane >> 3;       // sub-chunk 0..7

    if (tid < NE) { imp_lds[tid] = 0.f; cnt_lds[tid] = 0; }

    // w fragment: wf[k] = w[e][g*256 + (s+8k)*4 ..+4), k=0..7  (32 VGPRs, cached)
    const fvec4* w4    = (const fvec4*)wg;
    const fvec4* wbase = w4 + e * D4 + g * 64 + s;
    fvec4 wf[8];
#pragma unroll
    for (int k = 0; k < 8; k++) wf[k] = wbase[8 * k];

    const int tok0 = blockIdx.x * TOK_PER_BLOCK;
    const fvec4* xbase = (const fvec4*)x + (size_t)tok0 * D4 + g * 64 + s;

#define LOADX(dst, t)                                                     \
    {                                                                     \
        const fvec4* _p = xbase + (size_t)(t) * D4;                       \
        _Pragma("unroll")                                                 \
        for (int k = 0; k < 8; k++) dst[k] = ntload(_p + 8 * k);          \
    }

#define COMPUTE_STORE(src, t)                                             \
    {                                                                     \
        float acc = dot4(src[0], wf[0]);                                  \
        _Pragma("unroll")                                                 \
        for (int k = 1; k < 8; k++) acc += dot4(src[k], wf[k]);           \
        acc += __shfl_xor(acc, 8, 64);   /* reduce over s (bits 3..5) */  \
        acc += __shfl_xor(acc, 16, 64);                                   \
        acc += __shfl_xor(acc, 32, 64);                                   \
        if (lane < 8) part[t][g][lane] = acc;                             \
    }

    fvec4 A[8], B[8];
    LOADX(A, 0);
    __builtin_amdgcn_sched_barrier(0);   // all 8 loads issued before anything else

#pragma unroll 1
    for (int t = 0; t < TOK_PER_BLOCK; t += 2) {
        LOADX(B, t + 1);                       // next token's loads in flight
        __builtin_amdgcn_sched_barrier(0);     // don't sink them into compute
        COMPUTE_STORE(A, t);                   // waits vmcnt(8): only A's loads

        if (t + 2 < TOK_PER_BLOCK) LOADX(A, t + 2);
        __builtin_amdgcn_sched_barrier(0);
        COMPUTE_STORE(B, t + 1);
    }
#undef LOADX
#undef COMPUTE_STORE

    __syncthreads();

    // cross-wave reduce: thread (t,e) sums the 8 wave partials (<=2-way banks)
    if (tid < TOK_PER_BLOCK * NE) {
        const int tt = tid >> 3, ee = tid & 7;
        float sum = 0.f;
#pragma unroll
        for (int gg = 0; gg < 8; gg++) sum += part[tt][gg][ee];
        logits[tt][ee] = sum;
    }
    __syncthreads();

    // scalar phase: one thread per token (32 parallel tokens)
    if (tid < TOK_PER_BLOCK) {
        const int t = tok0 + tid;
        float v[NE];
#pragma unroll
        for (int k = 0; k < NE; k++) v[k] = logits[tid][k];

        // softmax over 8 (importance accumulation)
        float m = v[0];
#pragma unroll
        for (int k = 1; k < NE; k++) m = fmaxf(m, v[k]);
        float pe[NE], ssum = 0.f;
#pragma unroll
        for (int k = 0; k < NE; k++) { pe[k] = expf(v[k] - m); ssum += pe[k]; }
        const float inv = 1.f / ssum;
#pragma unroll
        for (int k = 0; k < NE; k++) atomicAdd(&imp_lds[k], pe[k] * inv);

        // top-2 (ties -> lowest index, jax top_k semantics)
        int i1 = 0; float v1 = v[0];
#pragma unroll
        for (int k = 1; k < NE; k++) { if (v[k] > v1) { v1 = v[k]; i1 = k; } }
        int i2 = -1; float v2 = -3.4e38f;
#pragma unroll
        for (int k = 0; k < NE; k++) { if (k != i1 && v[k] > v2) { v2 = v[k]; i2 = k; } }

        const float w1 = 1.f / (1.f + expf(v2 - v1));   // renormalized pair
        atomicAdd(&cnt_lds[i1], 1);
        atomicAdd(&cnt_lds[i2], 1);

        fvec2 oi; oi.x = (float)i1; oi.y = (float)i2;
        fvec2 ow; ow.x = w1;        ow.y = 1.f - w1;
        ((fvec2*)out_idx)[t] = oi;
        ((fvec2*)out_w)[t]   = ow;
    }

    __syncthreads();
    if (tid < NE)          atomicAdd(&imp_g[tid], imp_lds[tid]);
    else if (tid < 2 * NE) atomicAdd(&cnt_g[tid - NE], cnt_lds[tid - NE]);
}

// Capacity mask (exact rank rule, matches lexsort((-wf, idxf)) + rank<capacity)
// plus the load-balance loss scalar.
__global__ void mask_loss_kernel(
    const float* __restrict__ out_idx, const float* __restrict__ out_w,
    float* __restrict__ mask, float* __restrict__ loss_out,
    const float* __restrict__ imp_g, const int* __restrict__ cnt_g)
{
    const int i = blockIdx.x * blockDim.x + threadIdx.x;
    if (i < NASSIGN) {
        const int e = (int)out_idx[i];
        const int c = cnt_g[e];
        float mk = 1.f;
        if (c > CAPACITY) {   // statistically never taken; exact fallback
            const float wi = out_w[i];
            int rank = 0;
            for (int j = 0; j < NASSIGN; j++) {
                if ((int)out_idx[j] == e) {
                    const float wj = out_w[j];
                    if (wj > wi || (wj == wi && j < i)) rank++;
                }
            }
            mk = (rank < CAPACITY) ? 1.f : 0.f;
        }
        mask[i] = mk;
    }
    if (blockIdx.x == 0 && threadIdx.x == 0) {
        float si = 0.f, sc = 0.f, dot = 0.f;
#pragma unroll
        for (int e = 0; e < NE; e++) {
            const float im = imp_g[e];
            const float ct = (float)cnt_g[e];
            si += im; sc += ct; dot += im * ct;
        }
        loss_out[0] = (float)NE * dot / (si * sc);
    }
}

extern "C" void kernel_launch(void* const* d_in, const int* in_sizes, int n_in,
                              void* d_out, int out_size, void* d_ws, size_t ws_size,
                              hipStream_t stream)
{
    const float* x  = (const float*)d_in[0];   // [4,4096,2048] f32
    const float* wg = (const float*)d_in[1];   // [8,2048] f32

    float* out      = (float*)d_out;
    float* out_idx  = out;            // 32768
    float* out_w    = out + 32768;    // 32768
    float* loss     = out + 65536;    // 1
    float* mask     = out + 65537;    // 32768

    float* imp_g = (float*)d_ws;                     // 8 f32
    int*   cnt_g = (int*)((char*)d_ws + 64);         // 8 i32

    hipMemsetAsync(d_ws, 0, 128, stream);

    router_main<<<NBLOCKS, NTHREADS, 0, stream>>>(x, wg, out_idx, out_w, imp_g, cnt_g);
    mask_loss_kernel<<<(NASSIGN + NTHREADS - 1) / NTHREADS, NTHREADS, 0, stream>>>(
        out_idx, out_w, mask, loss, imp_g, cnt_g);
}